// Round 9
// baseline (531.227 us; speedup 1.0000x reference)
//
#include <hip/hip_runtime.h>

// ---------------- problem constants ----------------
constexpr int NB  = 32;     // batch
constexpr int NS  = 1024;   // seq
constexpr int NH  = 768;    // hidden
constexpr int NH2 = 1536;   // 2*hidden
constexpr int NQKV = 2304;  // 3*hidden
constexpr int NBS = NB * NS;

typedef __bf16 bf16x8 __attribute__((ext_vector_type(8)));
typedef float  f32x4  __attribute__((ext_vector_type(4)));
typedef unsigned short u16x8 __attribute__((ext_vector_type(8)));

__device__ __forceinline__ unsigned short f2bf(float f) {
  unsigned int u = __builtin_bit_cast(unsigned int, f);
  u += 0x7FFFu + ((u >> 16) & 1u);
  return (unsigned short)(u >> 16);
}
__device__ __forceinline__ float bf2f(unsigned short h) {
  return __builtin_bit_cast(float, ((unsigned int)h) << 16);
}

#define GLDS16(g, l)                                                         \
  __builtin_amdgcn_global_load_lds(                                          \
      (__attribute__((address_space(1))) void*)(g),                          \
      (__attribute__((address_space(3))) void*)(l), 16, 0, 0)

// ---------------- cond stage 0: gather + transpose ----------------
__launch_bounds__(256)
__global__ void cond_pre(const int* __restrict__ relation,
                         const float* __restrict__ h,
                         const int* __restrict__ subh,
                         const int* __restrict__ subt,
                         const float* __restrict__ rel_emb,
                         float* __restrict__ reT, float* __restrict__ condT) {
  const int b = blockIdx.x, t = threadIdx.x;
  const int r = relation[b], sh = subh[b], st = subt[b];
  for (int k = t; k < NH; k += 256) {
    reT[(size_t)k * NB + b] = rel_emb[(size_t)r * NH + k];
    condT[(size_t)(NH + k) * NB + b] =
        0.5f * (h[((size_t)b * NS + sh) * NH + k] +
                h[((size_t)b * NS + st) * NH + k]);
  }
}

// ---------------- cond stage 1: rel_feature = relu6(re @ W_rf^T + b_rf) ----
__launch_bounds__(256)
__global__ void cond_rf(const float* __restrict__ W_rf,
                        const float* __restrict__ b_rf,
                        const float* __restrict__ reT,
                        float* __restrict__ condT) {
  const int t = threadIdx.x;
  const int b = t & 31, jl = t >> 5;
  const int j = blockIdx.x * 8 + jl;
  const float4* w4 = (const float4*)(W_rf + (size_t)j * NH);
  const float* rT = reT + b;
  float a0 = 0.f, a1 = 0.f;
  for (int k4 = 0; k4 < NH / 4; k4++) {
    float4 w = w4[k4];
    const float* c = rT + (size_t)(k4 * 4) * NB;
    a0 += w.x * c[0] + w.y * c[NB];
    a1 += w.z * c[2 * NB] + w.w * c[3 * NB];
  }
  float acc = a0 + a1 + b_rf[j];
  condT[(size_t)j * NB + b] = fminf(fmaxf(acc, 0.0f), 6.0f);
}

// ---------------- cond stage 2: wt/bs = cond @ W_{wd,bd}^T + gamma/beta ----
__launch_bounds__(256)
__global__ void cond_wb(const float* __restrict__ W_wd,
                        const float* __restrict__ W_bd,
                        const float* __restrict__ gamma,
                        const float* __restrict__ beta,
                        const float* __restrict__ condT,
                        float* __restrict__ wt, float* __restrict__ bs) {
  __shared__ float redW[128], redB[128];
  const int t = threadIdx.x;
  const int b = t & 31, jl = (t >> 5) & 3, ks = t >> 7;
  const int j = blockIdx.x * 4 + jl;
  const float4* ww = (const float4*)(W_wd + (size_t)j * NH2 + ks * NH);
  const float4* wb = (const float4*)(W_bd + (size_t)j * NH2 + ks * NH);
  const float* cT = condT + (size_t)ks * NH * NB + b;
  float aw0 = 0.f, aw1 = 0.f, ab0 = 0.f, ab1 = 0.f;
  for (int k4 = 0; k4 < NH / 4; k4++) {
    float4 w = ww[k4];
    float4 v = wb[k4];
    const float* c = cT + (size_t)(k4 * 4) * NB;
    float c0 = c[0], c1 = c[NB], c2 = c[2 * NB], c3 = c[3 * NB];
    aw0 += w.x * c0 + w.y * c1;
    aw1 += w.z * c2 + w.w * c3;
    ab0 += v.x * c0 + v.y * c1;
    ab1 += v.z * c2 + v.w * c3;
  }
  float aw = aw0 + aw1, ab = ab0 + ab1;
  if (ks == 1) {
    redW[t - 128] = aw;
    redB[t - 128] = ab;
  }
  __syncthreads();
  if (ks == 0) {
    aw += redW[t];
    ab += redB[t];
    wt[(size_t)b * NH + j] = aw + gamma[j];
    bs[(size_t)b * NH + j] = ab + beta[j];
  }
}

// ---------------- conditional layernorm -> x (bf16) ----------------
__launch_bounds__(64)
__global__ void ln_kernel(const float* __restrict__ h,
                          const float* __restrict__ wt,
                          const float* __restrict__ bs,
                          unsigned short* __restrict__ xbf) {
  const int row = blockIdx.x;      // 0..NBS-1
  const int b = row >> 10;
  const int lane = threadIdx.x;    // 0..63
  const float4* hr = (const float4*)(h + (size_t)row * NH);
  float4 v0 = hr[lane], v1 = hr[lane + 64], v2 = hr[lane + 128];
  float sum = 0.f, sq = 0.f;
  {
    sum += v0.x + v0.y + v0.z + v0.w;
    sq  += v0.x * v0.x + v0.y * v0.y + v0.z * v0.z + v0.w * v0.w;
    sum += v1.x + v1.y + v1.z + v1.w;
    sq  += v1.x * v1.x + v1.y * v1.y + v1.z * v1.z + v1.w * v1.w;
    sum += v2.x + v2.y + v2.z + v2.w;
    sq  += v2.x * v2.x + v2.y * v2.y + v2.z * v2.z + v2.w * v2.w;
  }
  for (int off = 32; off > 0; off >>= 1) {
    sum += __shfl_xor(sum, off, 64);
    sq  += __shfl_xor(sq, off, 64);
  }
  const float mean = sum * (1.0f / NH);
  const float var  = sq * (1.0f / NH) - mean * mean;
  const float rstd = rsqrtf(var + 1e-12f);
  const float4* wr = (const float4*)(wt + (size_t)b * NH);
  const float4* br = (const float4*)(bs + (size_t)b * NH);
  ushort4* xr = (ushort4*)(xbf + (size_t)row * NH);
#pragma unroll
  for (int i = 0; i < 3; i++) {
    float4 v = (i == 0) ? v0 : (i == 1) ? v1 : v2;
    float4 w = wr[lane + 64 * i];
    float4 bb = br[lane + 64 * i];
    ushort4 o;
    o.x = f2bf((v.x - mean) * rstd * w.x + bb.x);
    o.y = f2bf((v.y - mean) * rstd * w.y + bb.y);
    o.z = f2bf((v.z - mean) * rstd * w.z + bb.z);
    o.w = f2bf((v.w - mean) * rstd * w.w + bb.w);
    xr[lane + 64 * i] = o;
  }
}

// ---------------- weight prep: Wq/Wk/Wv -> bf16 concat ----------------
__launch_bounds__(256)
__global__ void prep_w(const float* __restrict__ Wq, const float* __restrict__ bq,
                       const float* __restrict__ Wk, const float* __restrict__ bk,
                       const float* __restrict__ Wv, const float* __restrict__ bv,
                       unsigned short* __restrict__ Wcat, float* __restrict__ bcat) {
  const int row = blockIdx.x;  // 0..2303
  const float* Wsrc;
  const float* bsrc;
  int r;
  if (row < NH) { Wsrc = Wq; bsrc = bq; r = row; }
  else if (row < NH2) { Wsrc = Wk; bsrc = bk; r = row - NH; }
  else { Wsrc = Wv; bsrc = bv; r = row - NH2; }
  for (int j = threadIdx.x; j < NH; j += 256)
    Wcat[(size_t)row * NH + j] = f2bf(Wsrc[(size_t)r * NH + j]);
  if (threadIdx.x == 0) bcat[row] = bsrc[r];
}

// ================= 128x128 BK=32 4-wave GEMM: C = op(A @ B^T) =============
// m97-class structure + conflict-free swizzle + high occupancy.
// A: [M,K] bf16 lda; B: [N,K] bf16 ldb; C: [M,N].
// 4 waves (2M x 2N), per-wave 64x64 out (acc[4][4] = 64 VGPR), mfma 16x16x32.
// LDS 32 KiB: 2 dbuf x [A 128x64B | B 128x64B] -> with launch_bounds(256,4)
// (VGPR cap 128) FOUR independent blocks/CU = 16 waves. The per-tile
// __syncthreads drain (compiler emits vmcnt0+lgkm0+barrier) stalls only this
// block; 3 sibling blocks compute through it (m114 wave-level overlap - the
// mechanism behind m97's 912 TF). Swizzle (64B rows, 16B chunks): read chunk
// = hi ^ ((lr>>1)&3); LDS slot (row,c) holds global chunk c ^ ((row>>1)&3),
// staged via pre-swizzled global chunk (t&3)^((t>>3)&3), LDS dest linear.
// Measured 0 bank conflicts in R5 with this exact mapping.
template <int OUT_BF16, int RELU, int HASBIAS, int RES>
__launch_bounds__(256, 4)
__global__ void gemm128(const unsigned short* __restrict__ A, long long sAz, int lda,
                        const unsigned short* __restrict__ Bm, long long sBz, int ldb,
                        void* __restrict__ C, long long sCz, int ldc,
                        const float* __restrict__ bias,
                        const unsigned short* __restrict__ Res, long long sRz, int ldr,
                        int K) {
  __shared__ char lds[32768];  // buf b: A @ b*16384, B @ b*16384+8192
  const int t = threadIdx.x;
  const int z = blockIdx.z;
  // bijective XCD-aware swizzle over the xy-grid (per z)
  int id = blockIdx.x + blockIdx.y * gridDim.x;
  {
    const int nwg = gridDim.x * gridDim.y;
    const int q = nwg >> 3, r = nwg & 7;
    const int xcd = id & 7, lid = id >> 3;
    id = (xcd < r ? xcd * (q + 1) : r * (q + 1) + (xcd - r) * q) + lid;
  }
  const int tileN = (id % gridDim.x) * 128;
  const int tileM = (id / gridDim.x) * 128;
  const unsigned short* Ab = A + (size_t)z * sAz + (size_t)tileM * lda;
  const unsigned short* Bb = Bm + (size_t)z * sBz + (size_t)tileN * ldb;

  const int lane = t & 63;
  const int w = t >> 6;
  const int wm = w >> 1, wn = w & 1;       // wave grid 2M x 2N
  const int lr = lane & 15, hi = lane >> 4;
  const int cbyte = ((hi ^ ((lr >> 1) & 3)) << 4);  // read chunk byte in 64B row

  // staging: thread t -> rows (t>>2) and 64+(t>>2), LDS chunk (t&3),
  // pre-swizzled global chunk (t&3)^((t>>3)&3); LDS dest linear (t*16).
  const int sgc = (t & 3) ^ ((t >> 3) & 3);

#define STAGEOP(Gb, ld, kc, dst)                                            \
  do {                                                                      \
    GLDS16((Gb) + (size_t)(t >> 2) * (ld) + (kc) + sgc * 8,                 \
           (dst) + (size_t)t * 16);                                         \
    GLDS16((Gb) + (size_t)(64 + (t >> 2)) * (ld) + (kc) + sgc * 8,          \
           (dst) + 4096 + (size_t)t * 16);                                  \
  } while (0)

  f32x4 acc[4][4];
#pragma unroll
  for (int m = 0; m < 4; m++)
#pragma unroll
    for (int n = 0; n < 4; n++) acc[m][n] = (f32x4)0.0f;

  const int NT = K >> 5;  // K-tiles of 32

  // prologue: stage k0 -> buf0
  STAGEOP(Ab, lda, 0, lds);
  STAGEOP(Bb, ldb, 0, lds + 8192);
  __syncthreads();

  for (int kt = 0; kt < NT; kt++) {
    const int bb = kt & 1;
    const char* Ah = lds + bb * 16384;
    const char* Bh = Ah + 8192;
    // prefetch kt+1 into buf^1 (reads of buf^1 ended at the barrier
    // closing tile kt-1; loads fly while this tile computes)
    if (kt + 1 < NT) {
      STAGEOP(Ab, lda, (kt + 1) * 32, lds + (bb ^ 1) * 16384);
      STAGEOP(Bb, ldb, (kt + 1) * 32, lds + (bb ^ 1) * 16384 + 8192);
    }
    bf16x8 aF[4], bF[4];
#pragma unroll
    for (int i = 0; i < 4; i++)
      aF[i] = *(const bf16x8*)(Ah + (wm * 64 + i * 16 + lr) * 64 + cbyte);
#pragma unroll
    for (int j = 0; j < 4; j++)
      bF[j] = *(const bf16x8*)(Bh + (wn * 64 + j * 16 + lr) * 64 + cbyte);
#pragma unroll
    for (int i = 0; i < 4; i++)
#pragma unroll
      for (int j = 0; j < 4; j++)
        acc[i][j] = __builtin_amdgcn_mfma_f32_16x16x32_bf16(aF[i], bF[j],
                                                            acc[i][j], 0, 0, 0);
    __syncthreads();  // drains this block only; 3 sibling blocks cover it
  }

  // epilogue: C/D layout col=lane&15, row=(lane>>4)*4+reg  [m89-verified]
  const int row0 = tileM + wm * 64;
  const int col0 = tileN + wn * 64;
#pragma unroll
  for (int m = 0; m < 4; m++) {
    const int rowb = row0 + m * 16 + hi * 4;
#pragma unroll
    for (int n = 0; n < 4; n++) {
      const int col = col0 + n * 16 + lr;
      const float bv = HASBIAS ? bias[col] : 0.0f;
      f32x4 v = acc[m][n];
#pragma unroll
      for (int r = 0; r < 4; r++) {
        float x = v[r] + bv;
        if (RELU) x = fmaxf(x, 0.0f);
        if (RES)
          x += bf2f(Res[(size_t)z * sRz + (size_t)(rowb + r) * ldr + col]);
        if (OUT_BF16)
          ((unsigned short*)C)[(size_t)z * sCz + (size_t)(rowb + r) * ldc + col] =
              f2bf(x);
        else
          ((float*)C)[(size_t)z * sCz + (size_t)(rowb + r) * ldc + col] = x;
      }
    }
  }
#undef STAGEOP
}

// ---------------- softmax (in-place f32 row -> bf16 probs) ----------------
__launch_bounds__(256)
__global__ void softmax_kernel(float* __restrict__ e,
                               const float* __restrict__ mask, int b0) {
  const int ri = blockIdx.x;
  const int lb = blockIdx.y;
  const int b = b0 + lb;
  float* row = e + ((size_t)lb * NS + ri) * NS;
  const int t = threadIdx.x;
  float4 v = ((const float4*)row)[t];
  float4 m = ((const float4*)(mask + (size_t)b * NS))[t];
  v.x -= 1e10f * (1.0f - m.x);
  v.y -= 1e10f * (1.0f - m.y);
  v.z -= 1e10f * (1.0f - m.z);
  v.w -= 1e10f * (1.0f - m.w);
  float mx = fmaxf(fmaxf(v.x, v.y), fmaxf(v.z, v.w));
  __shared__ float red[4];
  for (int off = 32; off > 0; off >>= 1) mx = fmaxf(mx, __shfl_xor(mx, off, 64));
  if ((t & 63) == 0) red[t >> 6] = mx;
  __syncthreads();
  mx = fmaxf(fmaxf(red[0], red[1]), fmaxf(red[2], red[3]));
  const float e0 = __expf(v.x - mx), e1 = __expf(v.y - mx);
  const float e2 = __expf(v.z - mx), e3 = __expf(v.w - mx);
  float sm = e0 + e1 + e2 + e3;
  __syncthreads();  // everyone done reading red[] for max
  for (int off = 32; off > 0; off >>= 1) sm += __shfl_xor(sm, off, 64);
  if ((t & 63) == 0) red[t >> 6] = sm;
  __syncthreads();
  sm = red[0] + red[1] + red[2] + red[3];
  const float inv = 1.0f / sm;
  ushort4 o;
  o.x = f2bf(e0 * inv);
  o.y = f2bf(e1 * inv);
  o.z = f2bf(e2 * inv);
  o.w = f2bf(e3 * inv);
  ((ushort4*)row)[t] = o;  // all reads happened before barriers above
}

// ---------------- V transpose: v[b][s][h] -> vT[b][h][s] ----------------
__launch_bounds__(256)
__global__ void transpose_v(const unsigned short* __restrict__ qkv,
                            unsigned short* __restrict__ vT) {
  const int b = blockIdx.z;
  const int s0 = blockIdx.x * 64;
  const int h0 = blockIdx.y * 64;
  __shared__ unsigned short tile[64][72];
  const int t = threadIdx.x;
  const int tx = t & 7, ty = t >> 3;  // tx 0..7, ty 0..31
  const unsigned short* src = qkv + ((size_t)(b * NS + s0)) * NQKV + NH2 + h0;
#pragma unroll
  for (int i = 0; i < 2; i++) {
    const int s = ty + 32 * i;
    u16x8 vv = *(const u16x8*)(src + (size_t)s * NQKV + tx * 8);
#pragma unroll
    for (int j = 0; j < 8; j++) tile[s][tx * 8 + j] = vv[j];
  }
  __syncthreads();
  unsigned short* dst = vT + ((size_t)b * NH + h0) * NS + s0;
#pragma unroll
  for (int i = 0; i < 2; i++) {
    const int hh = ty + 32 * i;
    u16x8 o;
#pragma unroll
    for (int j = 0; j < 8; j++) o[j] = tile[tx * 8 + j][hh];
    *(u16x8*)(dst + (size_t)hh * NS + tx * 8) = o;
  }
}

// ---------------- head projection ----------------
__launch_bounds__(64)
__global__ void pred_kernel(const float* __restrict__ hidden,
                            const float* __restrict__ wobj,
                            const float* __restrict__ bobj,
                            float* __restrict__ pred) {
  const int row = blockIdx.x;
  const int lane = threadIdx.x;
  const float4* hr = (const float4*)(hidden + (size_t)row * NH);
  const float4* wr = (const float4*)wobj;
  float s = 0.f;
#pragma unroll
  for (int i = 0; i < 3; i++) {
    float4 a = hr[lane + 64 * i];
    float4 w = wr[lane + 64 * i];
    s += a.x * w.x + a.y * w.y + a.z * w.z + a.w * w.w;
  }
  for (int off = 32; off > 0; off >>= 1) s += __shfl_xor(s, off, 64);
  if (lane == 0) pred[row] = s + bobj[0];
}

// ---------------- launcher ----------------
extern "C" void kernel_launch(void* const* d_in, const int* in_sizes, int n_in,
                              void* d_out, int out_size, void* d_ws,
                              size_t ws_size, hipStream_t stream) {
  const int* relation   = (const int*)d_in[0];
  const float* lhs      = (const float*)d_in[1];
  const int* sub_head   = (const int*)d_in[2];
  const int* sub_tail   = (const int*)d_in[3];
  const float* att_mask = (const float*)d_in[4];
  const float* rel_emb  = (const float*)d_in[5];
  const float* W_rf     = (const float*)d_in[6];
  const float* b_rf     = (const float*)d_in[7];
  const float* gamma    = (const float*)d_in[8];
  const float* beta     = (const float*)d_in[9];
  const float* W_wd     = (const float*)d_in[10];
  const float* W_bd     = (const float*)d_in[11];
  const float* Wq       = (const float*)d_in[12];
  const float* bq       = (const float*)d_in[13];
  const float* Wk       = (const float*)d_in[14];
  const float* bk       = (const float*)d_in[15];
  const float* Wv       = (const float*)d_in[16];
  const float* bv       = (const float*)d_in[17];
  const float* W_obj    = (const float*)d_in[18];
  const float* b_obj    = (const float*)d_in[19];

  char* ws = (char*)d_ws;
  // offsets (all 256B aligned)
  unsigned short* Wcat = (unsigned short*)(ws + 0);          //  3,538,944
  float* bcat  = (float*)(ws + 3538944);                     //      9,216
  float* wt    = (float*)(ws + 3548160);                     //     98,304
  float* bs    = (float*)(ws + 3646464);                     //     98,304
  float* reT   = (float*)(ws + 3744768);                     //     98,304
  float* condT = (float*)(ws + 3843072);                     //    196,608
  unsigned short* xbf = (unsigned short*)(ws + 4039680);     // 50,331,648
  unsigned short* qkv = (unsigned short*)(ws + 54371328);    // 150,994,944
  unsigned short* vT  = (unsigned short*)(ws + 205366272);   // 50,331,648
  float* ebuf = (float*)(ws + 255697920);                    // CB*4,194,304

  float* out_pred = (float*)d_out;
  float* out_hidden = out_pred + NBS;

  const size_t fixed = 255697920ull;
  size_t avail = ws_size > fixed ? ws_size - fixed : 0;
  int CB = 32;
  while (CB > 1 && (size_t)CB * (size_t)NS * NS * 4 > avail) CB >>= 1;

  prep_w<<<dim3(NQKV), dim3(256), 0, stream>>>(Wq, bq, Wk, bk, Wv, bv, Wcat, bcat);
  cond_pre<<<dim3(NB), dim3(256), 0, stream>>>(relation, lhs, sub_head, sub_tail,
                                               rel_emb, reT, condT);
  cond_rf<<<dim3(NH / 8), dim3(256), 0, stream>>>(W_rf, b_rf, reT, condT);
  cond_wb<<<dim3(NH / 4), dim3(256), 0, stream>>>(W_wd, W_bd, gamma, beta, condT,
                                                  wt, bs);
  ln_kernel<<<dim3(NBS), dim3(64), 0, stream>>>(lhs, wt, bs, xbf);

  // QKV: [32768,768] @ Wcat[2304,768]^T -> relu(+bias) -> bf16 qkv [32768,2304]
  gemm128<1, 1, 1, 0><<<dim3(NQKV / 128, NBS / 128, 1), dim3(256), 0, stream>>>(
      xbf, 0, NH, Wcat, 0, NH, qkv, 0, NQKV, bcat, nullptr, 0, 0, NH);

  transpose_v<<<dim3(NS / 64, NH / 64, NB), dim3(256), 0, stream>>>(qkv, vT);

  for (int b0 = 0; b0 < NB; b0 += CB) {
    // scores: e = q @ k^T  (f32)
    gemm128<0, 0, 0, 0><<<dim3(NS / 128, NS / 128, CB), dim3(256), 0, stream>>>(
        qkv + (size_t)b0 * NS * NQKV, (long long)NS * NQKV, NQKV,
        qkv + (size_t)b0 * NS * NQKV + NH, (long long)NS * NQKV, NQKV,
        ebuf, (long long)NS * NS, NS, nullptr, nullptr, 0, 0, NH);
    // softmax rows in place -> bf16 probs (row stride stays 2048 bf16)
    softmax_kernel<<<dim3(NS, CB), dim3(256), 0, stream>>>(ebuf, att_mask, b0);
    // hidden = probs @ v + x   (vT is [H][S] so B^T pattern holds)
    gemm128<0, 0, 0, 1><<<dim3(NH / 128, NS / 128, CB), dim3(256), 0, stream>>>(
        (const unsigned short*)ebuf, (long long)NS * 2048, 2048,
        vT + (size_t)b0 * NH * NS, (long long)NH * NS, NS,
        out_hidden + (size_t)b0 * NS * NH, (long long)NS * NH, NH, nullptr,
        xbf + (size_t)b0 * NS * NH, (long long)NS * NH, NH, NS);
  }

  pred_kernel<<<dim3(NBS), dim3(64), 0, stream>>>(out_hidden, W_obj, b_obj,
                                                  out_pred);
}

// Round 10
// 504.104 us; speedup vs baseline: 1.0538x; 1.0538x over previous
//
#include <hip/hip_runtime.h>

// ---------------- problem constants ----------------
constexpr int NB  = 32;     // batch
constexpr int NS  = 1024;   // seq
constexpr int NH  = 768;    // hidden
constexpr int NH2 = 1536;   // 2*hidden
constexpr int NQKV = 2304;  // 3*hidden
constexpr int NBS = NB * NS;

typedef __bf16 bf16x8 __attribute__((ext_vector_type(8)));
typedef float  f32x4  __attribute__((ext_vector_type(4)));
typedef unsigned short u16x8 __attribute__((ext_vector_type(8)));

__device__ __forceinline__ unsigned short f2bf(float f) {
  unsigned int u = __builtin_bit_cast(unsigned int, f);
  u += 0x7FFFu + ((u >> 16) & 1u);
  return (unsigned short)(u >> 16);
}
__device__ __forceinline__ float bf2f(unsigned short h) {
  return __builtin_bit_cast(float, ((unsigned int)h) << 16);
}

#define GLDS16(g, l)                                                         \
  __builtin_amdgcn_global_load_lds(                                          \
      (__attribute__((address_space(1))) void*)(g),                          \
      (__attribute__((address_space(3))) void*)(l), 16, 0, 0)

// ---------------- cond stage 0: gather + transpose ----------------
__launch_bounds__(256)
__global__ void cond_pre(const int* __restrict__ relation,
                         const float* __restrict__ h,
                         const int* __restrict__ subh,
                         const int* __restrict__ subt,
                         const float* __restrict__ rel_emb,
                         float* __restrict__ reT, float* __restrict__ condT) {
  const int b = blockIdx.x, t = threadIdx.x;
  const int r = relation[b], sh = subh[b], st = subt[b];
  for (int k = t; k < NH; k += 256) {
    reT[(size_t)k * NB + b] = rel_emb[(size_t)r * NH + k];
    condT[(size_t)(NH + k) * NB + b] =
        0.5f * (h[((size_t)b * NS + sh) * NH + k] +
                h[((size_t)b * NS + st) * NH + k]);
  }
}

// ---------------- cond stage 1: rel_feature = relu6(re @ W_rf^T + b_rf) ----
__launch_bounds__(256)
__global__ void cond_rf(const float* __restrict__ W_rf,
                        const float* __restrict__ b_rf,
                        const float* __restrict__ reT,
                        float* __restrict__ condT) {
  const int t = threadIdx.x;
  const int b = t & 31, jl = t >> 5;
  const int j = blockIdx.x * 8 + jl;
  const float4* w4 = (const float4*)(W_rf + (size_t)j * NH);
  const float* rT = reT + b;
  float a0 = 0.f, a1 = 0.f;
  for (int k4 = 0; k4 < NH / 4; k4++) {
    float4 w = w4[k4];
    const float* c = rT + (size_t)(k4 * 4) * NB;
    a0 += w.x * c[0] + w.y * c[NB];
    a1 += w.z * c[2 * NB] + w.w * c[3 * NB];
  }
  float acc = a0 + a1 + b_rf[j];
  condT[(size_t)j * NB + b] = fminf(fmaxf(acc, 0.0f), 6.0f);
}

// ---------------- cond stage 2: wt/bs = cond @ W_{wd,bd}^T + gamma/beta ----
__launch_bounds__(256)
__global__ void cond_wb(const float* __restrict__ W_wd,
                        const float* __restrict__ W_bd,
                        const float* __restrict__ gamma,
                        const float* __restrict__ beta,
                        const float* __restrict__ condT,
                        float* __restrict__ wt, float* __restrict__ bs) {
  __shared__ float redW[128], redB[128];
  const int t = threadIdx.x;
  const int b = t & 31, jl = (t >> 5) & 3, ks = t >> 7;
  const int j = blockIdx.x * 4 + jl;
  const float4* ww = (const float4*)(W_wd + (size_t)j * NH2 + ks * NH);
  const float4* wb = (const float4*)(W_bd + (size_t)j * NH2 + ks * NH);
  const float* cT = condT + (size_t)ks * NH * NB + b;
  float aw0 = 0.f, aw1 = 0.f, ab0 = 0.f, ab1 = 0.f;
  for (int k4 = 0; k4 < NH / 4; k4++) {
    float4 w = ww[k4];
    float4 v = wb[k4];
    const float* c = cT + (size_t)(k4 * 4) * NB;
    float c0 = c[0], c1 = c[NB], c2 = c[2 * NB], c3 = c[3 * NB];
    aw0 += w.x * c0 + w.y * c1;
    aw1 += w.z * c2 + w.w * c3;
    ab0 += v.x * c0 + v.y * c1;
    ab1 += v.z * c2 + v.w * c3;
  }
  float aw = aw0 + aw1, ab = ab0 + ab1;
  if (ks == 1) {
    redW[t - 128] = aw;
    redB[t - 128] = ab;
  }
  __syncthreads();
  if (ks == 0) {
    aw += redW[t];
    ab += redB[t];
    wt[(size_t)b * NH + j] = aw + gamma[j];
    bs[(size_t)b * NH + j] = ab + beta[j];
  }
}

// ---------------- conditional layernorm -> x (bf16) ----------------
__launch_bounds__(64)
__global__ void ln_kernel(const float* __restrict__ h,
                          const float* __restrict__ wt,
                          const float* __restrict__ bs,
                          unsigned short* __restrict__ xbf) {
  const int row = blockIdx.x;      // 0..NBS-1
  const int b = row >> 10;
  const int lane = threadIdx.x;    // 0..63
  const float4* hr = (const float4*)(h + (size_t)row * NH);
  float4 v0 = hr[lane], v1 = hr[lane + 64], v2 = hr[lane + 128];
  float sum = 0.f, sq = 0.f;
  {
    sum += v0.x + v0.y + v0.z + v0.w;
    sq  += v0.x * v0.x + v0.y * v0.y + v0.z * v0.z + v0.w * v0.w;
    sum += v1.x + v1.y + v1.z + v1.w;
    sq  += v1.x * v1.x + v1.y * v1.y + v1.z * v1.z + v1.w * v1.w;
    sum += v2.x + v2.y + v2.z + v2.w;
    sq  += v2.x * v2.x + v2.y * v2.y + v2.z * v2.z + v2.w * v2.w;
  }
  for (int off = 32; off > 0; off >>= 1) {
    sum += __shfl_xor(sum, off, 64);
    sq  += __shfl_xor(sq, off, 64);
  }
  const float mean = sum * (1.0f / NH);
  const float var  = sq * (1.0f / NH) - mean * mean;
  const float rstd = rsqrtf(var + 1e-12f);
  const float4* wr = (const float4*)(wt + (size_t)b * NH);
  const float4* br = (const float4*)(bs + (size_t)b * NH);
  ushort4* xr = (ushort4*)(xbf + (size_t)row * NH);
#pragma unroll
  for (int i = 0; i < 3; i++) {
    float4 v = (i == 0) ? v0 : (i == 1) ? v1 : v2;
    float4 w = wr[lane + 64 * i];
    float4 bb = br[lane + 64 * i];
    ushort4 o;
    o.x = f2bf((v.x - mean) * rstd * w.x + bb.x);
    o.y = f2bf((v.y - mean) * rstd * w.y + bb.y);
    o.z = f2bf((v.z - mean) * rstd * w.z + bb.z);
    o.w = f2bf((v.w - mean) * rstd * w.w + bb.w);
    xr[lane + 64 * i] = o;
  }
}

// ---------------- weight prep: Wq/Wk/Wv -> bf16 concat ----------------
__launch_bounds__(256)
__global__ void prep_w(const float* __restrict__ Wq, const float* __restrict__ bq,
                       const float* __restrict__ Wk, const float* __restrict__ bk,
                       const float* __restrict__ Wv, const float* __restrict__ bv,
                       unsigned short* __restrict__ Wcat, float* __restrict__ bcat) {
  const int row = blockIdx.x;  // 0..2303
  const float* Wsrc;
  const float* bsrc;
  int r;
  if (row < NH) { Wsrc = Wq; bsrc = bq; r = row; }
  else if (row < NH2) { Wsrc = Wk; bsrc = bk; r = row - NH; }
  else { Wsrc = Wv; bsrc = bv; r = row - NH2; }
  for (int j = threadIdx.x; j < NH; j += 256)
    Wcat[(size_t)row * NH + j] = f2bf(Wsrc[(size_t)r * NH + j]);
  if (threadIdx.x == 0) bcat[row] = bsrc[r];
}

// ================= 128x128 BK=32 4-wave GEMM: C = op(A @ B^T) =============
// R9 structure (passed, 0 conflicts, 41% occupancy) with ONE change:
// FULL-3D bijective XCD swizzle. The flattened natural block id n (x fastest,
// then y, then z -- the HW dispatch order, round-robin across XCDs) is
// remapped so each XCD owns a CONTIGUOUS work range; decomposing work id with
// z slowest means an XCD processes whole batches sequentially. Co-resident
// blocks per XCD then span <=2 z's (~3-6 MB panels, ~L2-fit) instead of ~16
// z's (~48 MB L2 thrash; R9: scores/PV 2.4x slower per block than QKV with
// identical code -- L3 absorbed the re-fetches so FETCH stayed compulsory
// while staging latency doubled). For gridDim.z==1 (QKV) this mapping equals
// R9's 2-D swizzle exactly.
template <int OUT_BF16, int RELU, int HASBIAS, int RES>
__launch_bounds__(256, 4)
__global__ void gemm128(const unsigned short* __restrict__ A, long long sAz, int lda,
                        const unsigned short* __restrict__ Bm, long long sBz, int ldb,
                        void* __restrict__ C, long long sCz, int ldc,
                        const float* __restrict__ bias,
                        const unsigned short* __restrict__ Res, long long sRz, int ldr,
                        int K) {
  __shared__ char lds[32768];  // buf b: A @ b*16384, B @ b*16384+8192
  const int t = threadIdx.x;
  // full-3D bijective XCD-aware swizzle (nwg % 8 == 0 for all our grids)
  const int gx = gridDim.x, gxy = gridDim.x * gridDim.y;
  int n = blockIdx.x + gridDim.x * (blockIdx.y + gridDim.y * blockIdx.z);
  int wid;
  {
    const int nwg = gxy * gridDim.z;
    const int q = nwg >> 3, r = nwg & 7;
    const int xcd = n & 7, lid = n >> 3;
    wid = (xcd < r ? xcd * (q + 1) : r * (q + 1) + (xcd - r) * q) + lid;
  }
  const int z = wid / gxy;
  const int rem = wid % gxy;
  const int tileN = (rem % gx) * 128;
  const int tileM = (rem / gx) * 128;
  const unsigned short* Ab = A + (size_t)z * sAz + (size_t)tileM * lda;
  const unsigned short* Bb = Bm + (size_t)z * sBz + (size_t)tileN * ldb;

  const int lane = t & 63;
  const int w = t >> 6;
  const int wm = w >> 1, wn = w & 1;       // wave grid 2M x 2N
  const int lr = lane & 15, hi = lane >> 4;
  const int cbyte = ((hi ^ ((lr >> 1) & 3)) << 4);  // read chunk byte in 64B row

  // staging: thread t -> rows (t>>2) and 64+(t>>2), LDS chunk (t&3),
  // pre-swizzled global chunk (t&3)^((t>>3)&3); LDS dest linear (t*16).
  const int sgc = (t & 3) ^ ((t >> 3) & 3);

#define STAGEOP(Gb, ld, kc, dst)                                            \
  do {                                                                      \
    GLDS16((Gb) + (size_t)(t >> 2) * (ld) + (kc) + sgc * 8,                 \
           (dst) + (size_t)t * 16);                                         \
    GLDS16((Gb) + (size_t)(64 + (t >> 2)) * (ld) + (kc) + sgc * 8,          \
           (dst) + 4096 + (size_t)t * 16);                                  \
  } while (0)

  f32x4 acc[4][4];
#pragma unroll
  for (int m = 0; m < 4; m++)
#pragma unroll
    for (int n2 = 0; n2 < 4; n2++) acc[m][n2] = (f32x4)0.0f;

  const int NT = K >> 5;  // K-tiles of 32

  // prologue: stage k0 -> buf0
  STAGEOP(Ab, lda, 0, lds);
  STAGEOP(Bb, ldb, 0, lds + 8192);
  __syncthreads();

  for (int kt = 0; kt < NT; kt++) {
    const int bb = kt & 1;
    const char* Ah = lds + bb * 16384;
    const char* Bh = Ah + 8192;
    // prefetch kt+1 into buf^1 (reads of buf^1 ended at the barrier
    // closing tile kt-1; loads fly while this tile computes)
    if (kt + 1 < NT) {
      STAGEOP(Ab, lda, (kt + 1) * 32, lds + (bb ^ 1) * 16384);
      STAGEOP(Bb, ldb, (kt + 1) * 32, lds + (bb ^ 1) * 16384 + 8192);
    }
    bf16x8 aF[4], bF[4];
#pragma unroll
    for (int i = 0; i < 4; i++)
      aF[i] = *(const bf16x8*)(Ah + (wm * 64 + i * 16 + lr) * 64 + cbyte);
#pragma unroll
    for (int j = 0; j < 4; j++)
      bF[j] = *(const bf16x8*)(Bh + (wn * 64 + j * 16 + lr) * 64 + cbyte);
#pragma unroll
    for (int i = 0; i < 4; i++)
#pragma unroll
      for (int j = 0; j < 4; j++)
        acc[i][j] = __builtin_amdgcn_mfma_f32_16x16x32_bf16(aF[i], bF[j],
                                                            acc[i][j], 0, 0, 0);
    __syncthreads();  // drains this block only; 3 sibling blocks cover it
  }

  // epilogue: C/D layout col=lane&15, row=(lane>>4)*4+reg  [m89-verified]
  const int row0 = tileM + wm * 64;
  const int col0 = tileN + wn * 64;
#pragma unroll
  for (int m = 0; m < 4; m++) {
    const int rowb = row0 + m * 16 + hi * 4;
#pragma unroll
    for (int n2 = 0; n2 < 4; n2++) {
      const int col = col0 + n2 * 16 + lr;
      const float bv = HASBIAS ? bias[col] : 0.0f;
      f32x4 v = acc[m][n2];
#pragma unroll
      for (int r = 0; r < 4; r++) {
        float x = v[r] + bv;
        if (RELU) x = fmaxf(x, 0.0f);
        if (RES)
          x += bf2f(Res[(size_t)z * sRz + (size_t)(rowb + r) * ldr + col]);
        if (OUT_BF16)
          ((unsigned short*)C)[(size_t)z * sCz + (size_t)(rowb + r) * ldc + col] =
              f2bf(x);
        else
          ((float*)C)[(size_t)z * sCz + (size_t)(rowb + r) * ldc + col] = x;
      }
    }
  }
#undef STAGEOP
}

// ---------------- softmax (in-place f32 row -> bf16 probs) ----------------
__launch_bounds__(256)
__global__ void softmax_kernel(float* __restrict__ e,
                               const float* __restrict__ mask, int b0) {
  const int ri = blockIdx.x;
  const int lb = blockIdx.y;
  const int b = b0 + lb;
  float* row = e + ((size_t)lb * NS + ri) * NS;
  const int t = threadIdx.x;
  float4 v = ((const float4*)row)[t];
  float4 m = ((const float4*)(mask + (size_t)b * NS))[t];
  v.x -= 1e10f * (1.0f - m.x);
  v.y -= 1e10f * (1.0f - m.y);
  v.z -= 1e10f * (1.0f - m.z);
  v.w -= 1e10f * (1.0f - m.w);
  float mx = fmaxf(fmaxf(v.x, v.y), fmaxf(v.z, v.w));
  __shared__ float red[4];
  for (int off = 32; off > 0; off >>= 1) mx = fmaxf(mx, __shfl_xor(mx, off, 64));
  if ((t & 63) == 0) red[t >> 6] = mx;
  __syncthreads();
  mx = fmaxf(fmaxf(red[0], red[1]), fmaxf(red[2], red[3]));
  const float e0 = __expf(v.x - mx), e1 = __expf(v.y - mx);
  const float e2 = __expf(v.z - mx), e3 = __expf(v.w - mx);
  float sm = e0 + e1 + e2 + e3;
  __syncthreads();  // everyone done reading red[] for max
  for (int off = 32; off > 0; off >>= 1) sm += __shfl_xor(sm, off, 64);
  if ((t & 63) == 0) red[t >> 6] = sm;
  __syncthreads();
  sm = red[0] + red[1] + red[2] + red[3];
  const float inv = 1.0f / sm;
  ushort4 o;
  o.x = f2bf(e0 * inv);
  o.y = f2bf(e1 * inv);
  o.z = f2bf(e2 * inv);
  o.w = f2bf(e3 * inv);
  ((ushort4*)row)[t] = o;  // all reads happened before barriers above
}

// ---------------- V transpose: v[b][s][h] -> vT[b][h][s] ----------------
__launch_bounds__(256)
__global__ void transpose_v(const unsigned short* __restrict__ qkv,
                            unsigned short* __restrict__ vT) {
  const int b = blockIdx.z;
  const int s0 = blockIdx.x * 64;
  const int h0 = blockIdx.y * 64;
  __shared__ unsigned short tile[64][72];
  const int t = threadIdx.x;
  const int tx = t & 7, ty = t >> 3;  // tx 0..7, ty 0..31
  const unsigned short* src = qkv + ((size_t)(b * NS + s0)) * NQKV + NH2 + h0;
#pragma unroll
  for (int i = 0; i < 2; i++) {
    const int s = ty + 32 * i;
    u16x8 vv = *(const u16x8*)(src + (size_t)s * NQKV + tx * 8);
#pragma unroll
    for (int j = 0; j < 8; j++) tile[s][tx * 8 + j] = vv[j];
  }
  __syncthreads();
  unsigned short* dst = vT + ((size_t)b * NH + h0) * NS + s0;
#pragma unroll
  for (int i = 0; i < 2; i++) {
    const int hh = ty + 32 * i;
    u16x8 o;
#pragma unroll
    for (int j = 0; j < 8; j++) o[j] = tile[tx * 8 + j][hh];
    *(u16x8*)(dst + (size_t)hh * NS + tx * 8) = o;
  }
}

// ---------------- head projection ----------------
__launch_bounds__(64)
__global__ void pred_kernel(const float* __restrict__ hidden,
                            const float* __restrict__ wobj,
                            const float* __restrict__ bobj,
                            float* __restrict__ pred) {
  const int row = blockIdx.x;
  const int lane = threadIdx.x;
  const float4* hr = (const float4*)(hidden + (size_t)row * NH);
  const float4* wr = (const float4*)wobj;
  float s = 0.f;
#pragma unroll
  for (int i = 0; i < 3; i++) {
    float4 a = hr[lane + 64 * i];
    float4 w = wr[lane + 64 * i];
    s += a.x * w.x + a.y * w.y + a.z * w.z + a.w * w.w;
  }
  for (int off = 32; off > 0; off >>= 1) s += __shfl_xor(s, off, 64);
  if (lane == 0) pred[row] = s + bobj[0];
}

// ---------------- launcher ----------------
extern "C" void kernel_launch(void* const* d_in, const int* in_sizes, int n_in,
                              void* d_out, int out_size, void* d_ws,
                              size_t ws_size, hipStream_t stream) {
  const int* relation   = (const int*)d_in[0];
  const float* lhs      = (const float*)d_in[1];
  const int* sub_head   = (const int*)d_in[2];
  const int* sub_tail   = (const int*)d_in[3];
  const float* att_mask = (const float*)d_in[4];
  const float* rel_emb  = (const float*)d_in[5];
  const float* W_rf     = (const float*)d_in[6];
  const float* b_rf     = (const float*)d_in[7];
  const float* gamma    = (const float*)d_in[8];
  const float* beta     = (const float*)d_in[9];
  const float* W_wd     = (const float*)d_in[10];
  const float* W_bd     = (const float*)d_in[11];
  const float* Wq       = (const float*)d_in[12];
  const float* bq       = (const float*)d_in[13];
  const float* Wk       = (const float*)d_in[14];
  const float* bk       = (const float*)d_in[15];
  const float* Wv       = (const float*)d_in[16];
  const float* bv       = (const float*)d_in[17];
  const float* W_obj    = (const float*)d_in[18];
  const float* b_obj    = (const float*)d_in[19];

  char* ws = (char*)d_ws;
  // offsets (all 256B aligned)
  unsigned short* Wcat = (unsigned short*)(ws + 0);          //  3,538,944
  float* bcat  = (float*)(ws + 3538944);                     //      9,216
  float* wt    = (float*)(ws + 3548160);                     //     98,304
  float* bs    = (float*)(ws + 3646464);                     //     98,304
  float* reT   = (float*)(ws + 3744768);                     //     98,304
  float* condT = (float*)(ws + 3843072);                     //    196,608
  unsigned short* xbf = (unsigned short*)(ws + 4039680);     // 50,331,648
  unsigned short* qkv = (unsigned short*)(ws + 54371328);    // 150,994,944
  unsigned short* vT  = (unsigned short*)(ws + 205366272);   // 50,331,648
  float* ebuf = (float*)(ws + 255697920);                    // CB*4,194,304

  float* out_pred = (float*)d_out;
  float* out_hidden = out_pred + NBS;

  const size_t fixed = 255697920ull;
  size_t avail = ws_size > fixed ? ws_size - fixed : 0;
  int CB = 32;
  while (CB > 1 && (size_t)CB * (size_t)NS * NS * 4 > avail) CB >>= 1;

  prep_w<<<dim3(NQKV), dim3(256), 0, stream>>>(Wq, bq, Wk, bk, Wv, bv, Wcat, bcat);
  cond_pre<<<dim3(NB), dim3(256), 0, stream>>>(relation, lhs, sub_head, sub_tail,
                                               rel_emb, reT, condT);
  cond_rf<<<dim3(NH / 8), dim3(256), 0, stream>>>(W_rf, b_rf, reT, condT);
  cond_wb<<<dim3(NH / 4), dim3(256), 0, stream>>>(W_wd, W_bd, gamma, beta, condT,
                                                  wt, bs);
  ln_kernel<<<dim3(NBS), dim3(64), 0, stream>>>(lhs, wt, bs, xbf);

  // QKV: [32768,768] @ Wcat[2304,768]^T -> relu(+bias) -> bf16 qkv [32768,2304]
  gemm128<1, 1, 1, 0><<<dim3(NQKV / 128, NBS / 128, 1), dim3(256), 0, stream>>>(
      xbf, 0, NH, Wcat, 0, NH, qkv, 0, NQKV, bcat, nullptr, 0, 0, NH);

  transpose_v<<<dim3(NS / 64, NH / 64, NB), dim3(256), 0, stream>>>(qkv, vT);

  for (int b0 = 0; b0 < NB; b0 += CB) {
    // scores: e = q @ k^T  (f32)
    gemm128<0, 0, 0, 0><<<dim3(NS / 128, NS / 128, CB), dim3(256), 0, stream>>>(
        qkv + (size_t)b0 * NS * NQKV, (long long)NS * NQKV, NQKV,
        qkv + (size_t)b0 * NS * NQKV + NH, (long long)NS * NQKV, NQKV,
        ebuf, (long long)NS * NS, NS, nullptr, nullptr, 0, 0, NH);
    // softmax rows in place -> bf16 probs (row stride stays 2048 bf16)
    softmax_kernel<<<dim3(NS, CB), dim3(256), 0, stream>>>(ebuf, att_mask, b0);
    // hidden = probs @ v + x   (vT is [H][S] so B^T pattern holds)
    gemm128<0, 0, 0, 1><<<dim3(NH / 128, NS / 128, CB), dim3(256), 0, stream>>>(
        (const unsigned short*)ebuf, (long long)NS * 2048, 2048,
        vT + (size_t)b0 * NH * NS, (long long)NH * NS, NS,
        out_hidden + (size_t)b0 * NS * NH, (long long)NS * NH, NH, nullptr,
        xbf + (size_t)b0 * NS * NH, (long long)NS * NH, NH, NS);
  }

  pred_kernel<<<dim3(NBS), dim3(64), 0, stream>>>(out_hidden, W_obj, b_obj,
                                                  out_pred);
}